// Round 5
// baseline (114.147 us; speedup 1.0000x reference)
//
#include <hip/hip_runtime.h>
#include <math.h>

#define BLOCK 256
#define KTOP 7            // track top-(K+2)=7 of ALL values; remove positive by value at the end

// Branchless sorted-desc top-7 insert + exp-sum for one float4.
// t[k] = med3(t[k-1], t[k], x) is exactly the sorted-insert step given t[k-1] >= t[k].
__device__ __forceinline__ void proc4(const float4 v, float& s, float t[KTOP]) {
    float vals[4] = {v.x, v.y, v.z, v.w};
#pragma unroll
    for (int c = 0; c < 4; ++c) {
        const float x = vals[c];
        s += __expf(x);
#pragma unroll
        for (int k = KTOP - 1; k >= 1; --k)          // in-place high->low uses old t[k-1]
            t[k] = __builtin_amdgcn_fmed3f(t[k - 1], t[k], x);
        t[0] = fmaxf(t[0], x);
    }
}

// Full per-row pipeline: stream row, top-7 + exp-sum, block-merge, return loss (valid in tid 0).
__device__ __forceinline__ float row_loss_compute(const float* __restrict__ prow, int C,
                                                  float red[BLOCK][9], int tid) {
    const float4* p4 = (const float4*)prow;
    const int nvec = C >> 2;

    float t[KTOP];
#pragma unroll
    for (int k = 0; k < KTOP; ++k) t[k] = -INFINITY;
    float s0 = 0.f, s1 = 0.f, s2 = 0.f, s3 = 0.f;

    // 8 independent float4 loads in flight per iteration (MLP=8)
    int i = tid;
    for (; i + 7 * BLOCK < nvec; i += 8 * BLOCK) {
        float4 a = p4[i];
        float4 b = p4[i + BLOCK];
        float4 c = p4[i + 2 * BLOCK];
        float4 d = p4[i + 3 * BLOCK];
        float4 e = p4[i + 4 * BLOCK];
        float4 f = p4[i + 5 * BLOCK];
        float4 g = p4[i + 6 * BLOCK];
        float4 h = p4[i + 7 * BLOCK];
        proc4(a, s0, t);
        proc4(b, s1, t);
        proc4(c, s2, t);
        proc4(d, s3, t);
        proc4(e, s0, t);
        proc4(f, s1, t);
        proc4(g, s2, t);
        proc4(h, s3, t);
    }
    for (; i < nvec; i += BLOCK) proc4(p4[i], s0, t);
    const float s = (s0 + s1) + (s2 + s3);

    // Block reduction: merge sorted top-7 lists + sum (stride 9: conflict-free).
#pragma unroll
    for (int k = 0; k < KTOP; ++k) red[tid][k] = t[k];
    red[tid][KTOP] = s;
    __syncthreads();

    for (int half = BLOCK / 2; half >= 1; half >>= 1) {
        if (tid < half) {
            float a[KTOP], b[KTOP];
#pragma unroll
            for (int k = 0; k < KTOP; ++k) {
                a[k] = red[tid][k];
                b[k] = red[tid + half][k];
            }
            float c[KTOP];
#pragma unroll
            for (int k = 0; k < KTOP; ++k) {
                float best = -INFINITY;
#pragma unroll
                for (int m = 0; m <= k + 1; ++m) {
                    const int bi = (k - m) >= 0 ? (k - m) : 0;
                    float av = (m > 0) ? a[m - 1] : INFINITY;
                    float bv = ((k + 1 - m) > 0) ? b[bi] : INFINITY;
                    best = fmaxf(best, fminf(av, bv));
                }
                c[k] = best;
            }
#pragma unroll
            for (int k = 0; k < KTOP; ++k) red[tid][k] = c[k];
            red[tid][KTOP] = red[tid][KTOP] + red[tid + half][KTOP];
        }
        __syncthreads();
    }

    float loss = 0.0f;
    if (tid == 0) {
        float m[KTOP];
#pragma unroll
        for (int k = 0; k < KTOP; ++k) m[k] = red[0][k];
        const float S   = red[0][KTOP];
        const float inv = 1.0f / S;
        const float py  = prow[31999 < C ? 0 : 0];   // placeholder, replaced below
        (void)py;
        loss = S * inv; // placeholder (never used; real computation below in caller needs py)
    }
    return loss;
}

__global__ __launch_bounds__(BLOCK)
void autkc_fused2_kernel(const float* __restrict__ pred,
                         const int* __restrict__ y,
                         float* __restrict__ row_loss,
                         unsigned int* __restrict__ ticket,
                         float* __restrict__ out,
                         int C, int B, int NB) {
    const int tid = threadIdx.x;
    const int bid = blockIdx.x;
    const int HALF = NB;                 // NB == B/2 blocks; rows bid and bid+HALF

    __shared__ float red[BLOCK][9];

#pragma unroll 1
    for (int rr = 0; rr < 2; ++rr) {
        const int row = bid + rr * HALF;
        const float* prow = pred + (size_t)row * (size_t)C;
        const int yy = y[row];           // uniform
        const float py = prow[yy];       // positive-class logit, issued early

        const float4* p4 = (const float4*)prow;
        const int nvec = C >> 2;

        float t[KTOP];
#pragma unroll
        for (int k = 0; k < KTOP; ++k) t[k] = -INFINITY;
        float s0 = 0.f, s1 = 0.f, s2 = 0.f, s3 = 0.f;

        int i = tid;
        for (; i + 7 * BLOCK < nvec; i += 8 * BLOCK) {
            float4 a = p4[i];
            float4 b = p4[i + BLOCK];
            float4 c = p4[i + 2 * BLOCK];
            float4 d = p4[i + 3 * BLOCK];
            float4 e = p4[i + 4 * BLOCK];
            float4 f = p4[i + 5 * BLOCK];
            float4 g = p4[i + 6 * BLOCK];
            float4 h = p4[i + 7 * BLOCK];
            proc4(a, s0, t);
            proc4(b, s1, t);
            proc4(c, s2, t);
            proc4(d, s3, t);
            proc4(e, s0, t);
            proc4(f, s1, t);
            proc4(g, s2, t);
            proc4(h, s3, t);
        }
        for (; i < nvec; i += BLOCK) proc4(p4[i], s0, t);
        const float s = (s0 + s1) + (s2 + s3);

        // Block reduction: merge sorted top-7 lists + sum.
        __syncthreads();                 // protect red[] from previous row's readers
#pragma unroll
        for (int k = 0; k < KTOP; ++k) red[tid][k] = t[k];
        red[tid][KTOP] = s;
        __syncthreads();

        for (int half = BLOCK / 2; half >= 1; half >>= 1) {
            if (tid < half) {
                float a[KTOP], b[KTOP];
#pragma unroll
                for (int k = 0; k < KTOP; ++k) {
                    a[k] = red[tid][k];
                    b[k] = red[tid + half][k];
                }
                float c[KTOP];
#pragma unroll
                for (int k = 0; k < KTOP; ++k) {
                    float best = -INFINITY;
#pragma unroll
                    for (int m = 0; m <= k + 1; ++m) {
                        const int bi = (k - m) >= 0 ? (k - m) : 0;
                        float av = (m > 0) ? a[m - 1] : INFINITY;
                        float bv = ((k + 1 - m) > 0) ? b[bi] : INFINITY;
                        best = fmaxf(best, fminf(av, bv));
                    }
                    c[k] = best;
                }
#pragma unroll
                for (int k = 0; k < KTOP; ++k) red[tid][k] = c[k];
                red[tid][KTOP] = red[tid][KTOP] + red[tid + half][KTOP];
            }
            __syncthreads();
        }

        if (tid == 0) {
            float m[KTOP];
#pragma unroll
            for (int k = 0; k < KTOP; ++k) m[k] = red[0][k];
            const float S   = red[0][KTOP];
            const float inv = 1.0f / S;
            const float pp  = __expf(py) * inv;

            int r = KTOP;                    // remove one occurrence of py
#pragma unroll
            for (int k = KTOP - 1; k >= 0; --k)
                if (m[k] == py) r = k;

            float acc = 0.0f;
#pragma unroll
            for (int j = 0; j < 6; ++j) {    // K+1 = 6 top negatives
                const float nv = (j < r) ? m[j] : m[j + 1];
                const float d  = 1.0f + __expf(nv) * inv - pp;
                acc += d * d;
            }
            // RELAXED AGENT atomic store: sc1 write-through to the coherence
            // point. No L2 flush (this is what made R3 slow).
            __hip_atomic_store(&row_loss[row], acc * 0.2f,
                               __ATOMIC_RELAXED, __HIP_MEMORY_SCOPE_AGENT);
        }
    }

    // Last-block-done, fence-free: order store-completion before the ticket
    // with a raw vmcnt wait in tid0's instruction stream.
    __shared__ int is_last;
    if (tid == 0) {
        asm volatile("s_waitcnt vmcnt(0)" ::: "memory");
        const unsigned int old =
            __hip_atomic_fetch_add(ticket, 1u, __ATOMIC_RELAXED, __HIP_MEMORY_SCOPE_AGENT);
        is_last = (old == (unsigned int)(NB - 1)) ? 1 : 0;
    }
    __syncthreads();

    if (is_last) {
        // Fixed-order mean over B row losses -> deterministic output.
        float acc = 0.0f;
        for (int j = tid; j < B; j += BLOCK)
            acc += __hip_atomic_load(&row_loss[j], __ATOMIC_RELAXED, __HIP_MEMORY_SCOPE_AGENT);
        __shared__ float sh[BLOCK];
        sh[tid] = acc;
        __syncthreads();
        for (int half = BLOCK / 2; half >= 1; half >>= 1) {
            if (tid < half) sh[tid] += sh[tid + half];
            __syncthreads();
        }
        if (tid == 0) out[0] = sh[0] / (float)B;
    }
}

extern "C" void kernel_launch(void* const* d_in, const int* in_sizes, int n_in,
                              void* d_out, int out_size, void* d_ws, size_t ws_size,
                              hipStream_t stream) {
    const float* pred = (const float*)d_in[0];
    const int*   y    = (const int*)d_in[1];
    // d_in[2] = epoch (unused: epoch >= epoch_to_paced always takes the AUTKC branch)

    const int B = in_sizes[1];
    const int C = in_sizes[0] / B;
    const int NB = B / 2;                                 // 2 rows per block

    float* row_loss = (float*)d_ws;                       // B floats of scratch
    const size_t cnt_off = (((size_t)B * 4 + 255) / 256) * 256;
    unsigned int* ticket = (unsigned int*)((char*)d_ws + cnt_off);

    hipMemsetAsync(ticket, 0, sizeof(unsigned int), stream);  // per-call reset

    autkc_fused2_kernel<<<NB, BLOCK, 0, stream>>>(pred, y, row_loss, ticket,
                                                  (float*)d_out, C, B, NB);
}

// Round 6
// 99.713 us; speedup vs baseline: 1.1448x; 1.1448x over previous
//
#include <hip/hip_runtime.h>
#include <math.h>

#define BLOCK 256
#define KTOP 7            // top-(K+2)=7 of ALL values; remove positive by value at the end
#define RBLK 1024
#define THR  3.0f         // candidate threshold: E[#>3.0] ~= 43 per row of 32000 N(0,1)
#define CAP  512          // LDS candidate capacity (P[overflow] ~ 0; fallback if hit)

// Branchless sorted-desc top-7 insert for one float4 (fallback path only).
__device__ __forceinline__ void insert4(const float4 v, float t[KTOP]) {
    float vals[4] = {v.x, v.y, v.z, v.w};
#pragma unroll
    for (int c = 0; c < 4; ++c) {
        const float x = vals[c];
#pragma unroll
        for (int k = KTOP - 1; k >= 1; --k)
            t[k] = __builtin_amdgcn_fmed3f(t[k - 1], t[k], x);
        t[0] = fmaxf(t[0], x);
    }
}

// Streaming op: exp-sum + rare candidate push.
__device__ __forceinline__ void fsum4(const float4 v, float& s,
                                      int* cnt, float* cand) {
    float vals[4] = {v.x, v.y, v.z, v.w};
#pragma unroll
    for (int c = 0; c < 4; ++c) {
        const float x = vals[c];
        s += __expf(x);
        if (x > THR) {                       // rare (p ~= 0.00135/lane)
            const int idx = atomicAdd(cnt, 1);   // LDS atomic
            if (idx < CAP) cand[idx] = x;
        }
    }
}

__global__ __launch_bounds__(BLOCK)
void autkc_row_kernel(const float* __restrict__ pred,
                      const int* __restrict__ y,
                      float* __restrict__ row_loss,
                      int C) {
    const int row = blockIdx.x;
    const int tid = threadIdx.x;
    const float* prow = pred + (size_t)row * (size_t)C;
    const float4* p4 = (const float4*)prow;
    const int nvec = C >> 2;

    const int yy = y[row];          // uniform
    const float py = prow[yy];      // positive-class logit (uniform load, issued early)

    __shared__ int cnt;
    __shared__ float cand[CAP];
    if (tid == 0) cnt = 0;
    __syncthreads();

    float s0 = 0.f, s1 = 0.f, s2 = 0.f, s3 = 0.f;   // break the exp-sum dep chain

    // 4 independent float4 loads in flight; streaming VALU is just mul+exp+add+cmp.
    int i = tid;
    for (; i + 3 * BLOCK < nvec; i += 4 * BLOCK) {
        float4 a = p4[i];
        float4 b = p4[i + BLOCK];
        float4 c = p4[i + 2 * BLOCK];
        float4 d = p4[i + 3 * BLOCK];
        fsum4(a, s0, &cnt, cand);
        fsum4(b, s1, &cnt, cand);
        fsum4(c, s2, &cnt, cand);
        fsum4(d, s3, &cnt, cand);
    }
    for (; i < nvec; i += BLOCK) fsum4(p4[i], s0, &cnt, cand);
    const float s = (s0 + s1) + (s2 + s3);   // same order as R4 -> bitwise-identical sum

    __syncthreads();                 // cand[], cnt visible
    const int n = cnt;

    // Per-thread sorted-desc 7-list from candidates (or full rescan fallback).
    float t[KTOP];
    if (n >= KTOP && n <= CAP) {
        const float c0 = (tid < n) ? cand[tid] : -INFINITY;
        const float c1 = (tid + BLOCK < n) ? cand[tid + BLOCK] : -INFINITY;
        t[0] = fmaxf(c0, c1);
        t[1] = fminf(c0, c1);
#pragma unroll
        for (int k = 2; k < KTOP; ++k) t[k] = -INFINITY;
    } else {
        // Deterministic fallback: full med3 scan (never taken for N(0,1) data).
#pragma unroll
        for (int k = 0; k < KTOP; ++k) t[k] = -INFINITY;
        for (int j = tid; j < nvec; j += BLOCK) insert4(p4[j], t);
    }

    // Block reduction: merge sorted top-7 lists + sum (stride 9: conflict-free).
    __shared__ float red[BLOCK][9];
#pragma unroll
    for (int k = 0; k < KTOP; ++k) red[tid][k] = t[k];
    red[tid][KTOP] = s;
    __syncthreads();

    for (int half = BLOCK / 2; half >= 1; half >>= 1) {
        if (tid < half) {
            float a[KTOP], b[KTOP];
#pragma unroll
            for (int k = 0; k < KTOP; ++k) {
                a[k] = red[tid][k];
                b[k] = red[tid + half][k];
            }
            // (k+1)-th largest of union of two sorted lists: max over splits of min(heads)
            float c[KTOP];
#pragma unroll
            for (int k = 0; k < KTOP; ++k) {
                float best = -INFINITY;
#pragma unroll
                for (int m = 0; m <= k + 1; ++m) {
                    const int bi = (k - m) >= 0 ? (k - m) : 0;
                    float av = (m > 0) ? a[m - 1] : INFINITY;
                    float bv = ((k + 1 - m) > 0) ? b[bi] : INFINITY;
                    best = fmaxf(best, fminf(av, bv));
                }
                c[k] = best;
            }
#pragma unroll
            for (int k = 0; k < KTOP; ++k) red[tid][k] = c[k];
            red[tid][KTOP] = red[tid][KTOP] + red[tid + half][KTOP];
        }
        __syncthreads();
    }

    if (tid == 0) {
        float m[KTOP];
#pragma unroll
        for (int k = 0; k < KTOP; ++k) m[k] = red[0][k];
        const float S   = red[0][KTOP];
        const float inv = 1.0f / S;
        const float pp  = __expf(py) * inv;

        // remove one occurrence of py (the positive) from the top-7 list
        int r = KTOP;                    // KTOP = "not present"
#pragma unroll
        for (int k = KTOP - 1; k >= 0; --k)
            if (m[k] == py) r = k;       // smallest matching index wins

        float acc = 0.0f;
#pragma unroll
        for (int j = 0; j < 6; ++j) {    // K+1 = 6 top negatives
            const float nv = (j < r) ? m[j] : m[j + 1];
            const float d  = 1.0f + __expf(nv) * inv - pp;   // 'Sq' surrogate
            acc += d * d;
        }
        row_loss[row] = acc * 0.2f;      // / K
    }
}

__global__ __launch_bounds__(RBLK)
void autkc_reduce_kernel(const float* __restrict__ row_loss,
                         float* __restrict__ out, int B) {
    __shared__ float sh[RBLK];
    const int tid = threadIdx.x;
    float s = 0.0f;
    const int n4 = B >> 2;
    const float4* r4 = (const float4*)row_loss;
    for (int i = tid; i < n4; i += RBLK) {           // fixed order: deterministic
        float4 v = r4[i];
        s += (v.x + v.y) + (v.z + v.w);
    }
    for (int i = (n4 << 2) + tid; i < B; i += RBLK) s += row_loss[i];
    sh[tid] = s;
    __syncthreads();
    for (int half = RBLK / 2; half >= 1; half >>= 1) {
        if (tid < half) sh[tid] += sh[tid + half];
        __syncthreads();
    }
    if (tid == 0) out[0] = sh[0] / (float)B;
}

extern "C" void kernel_launch(void* const* d_in, const int* in_sizes, int n_in,
                              void* d_out, int out_size, void* d_ws, size_t ws_size,
                              hipStream_t stream) {
    const float* pred = (const float*)d_in[0];
    const int*   y    = (const int*)d_in[1];
    // d_in[2] = epoch (unused: epoch >= epoch_to_paced always takes the AUTKC branch)

    const int B = in_sizes[1];
    const int C = in_sizes[0] / B;

    float* row_loss = (float*)d_ws;     // B floats of scratch

    autkc_row_kernel<<<B, BLOCK, 0, stream>>>(pred, y, row_loss, C);
    autkc_reduce_kernel<<<1, RBLK, 0, stream>>>(row_loss, (float*)d_out, B);
}